// Round 16
// baseline (90.611 us; speedup 1.0000x reference)
//
#include <hip/hip_runtime.h>

// GCN layer: out = D^-1/2 (A + I) D^-1/2 (X W) + b
// N=50000, E=800000, 128 ch. MFMA bf16 GEMM + bf16 quartered gather table.
// History: R3 counting-sort CSR; R5 packed ebuf/csr; R6 agg masked unroll-8;
// R7 FAILED grid barriers; R8 FAILED fold race; R9 triangular colscan 48us;
// R11 coltot-from-hist 82.3; R12 ILP/TLP regression; R13/R14 flat; R15 XCD-
// quartered table 81.1 (best).
// R16: R15 quartering + R14 overlap, combined. dinv folded at AGG (4x-redundant
//      gather, cheap) so gemm is dinv-free and overlaps the CSR chain:
//      K1[hist || packw] -> K2[binscatter(self-bases) || gemm] -> K3[bucket_csr]
//      -> K4[agg]. ebuf un-aliased (K2 writes ebuf and xwq concurrently).

constexpr int CH = 128;
constexpr int CHUNK = 4096;    // edges per binning block
constexpr int NCMAX = 256;     // max coarse buckets (256 nodes each -> N <= 65536)
constexpr int HP = 256;        // h row pitch (ints) -> 16B-aligned int4 rows

typedef __attribute__((ext_vector_type(8))) short short8;
typedef __attribute__((ext_vector_type(4))) float f32x4;

static __device__ __forceinline__ ushort f2bf(float f) {
    unsigned u = __float_as_uint(f);
    u += 0x7fff + ((u >> 16) & 1);   // RNE
    return (ushort)(u >> 16);
}

// ---- K1: hist (blocks [0,nblk)) || pack_w (blocks [nblk,nblk+8)) --------

__global__ __launch_bounds__(256) void hist_packw(const int* __restrict__ dst,
        int* __restrict__ h, int* __restrict__ coltot,
        const float* __restrict__ Wm, ushort* __restrict__ Wp,
        int E, int nc, int nblk) {
    int t = threadIdx.x, b = blockIdx.x;
    if (b >= nblk) {
        int tid = (b - nblk) * 256 + t;   // 0..2047
        if (tid < 2048) {
            int col = tid >> 4, ch16 = tid & 15;
            ushort tmp[8];
            #pragma unroll
            for (int i = 0; i < 8; ++i)
                tmp[i] = f2bf(Wm[(size_t)(ch16 * 8 + i) * CH + col]);
            int d = col * 16 + (ch16 ^ (col & 7));
            *(uint4*)&Wp[(size_t)d * 8] = *(uint4*)tmp;
        }
        return;
    }
    __shared__ int hh[NCMAX];
    for (int i = t; i < NCMAX; i += 256) hh[i] = 0;
    __syncthreads();
    int s = b * CHUNK, e = min(E, s + CHUNK);
    for (int i = s + t * 4; i < e; i += 1024) {
        if (i + 4 <= e) {
            int4 v = *(const int4*)&dst[i];
            atomicAdd(&hh[v.x >> 8], 1);
            atomicAdd(&hh[v.y >> 8], 1);
            atomicAdd(&hh[v.z >> 8], 1);
            atomicAdd(&hh[v.w >> 8], 1);
        } else {
            for (int k = i; k < e; ++k) atomicAdd(&hh[dst[k] >> 8], 1);
        }
    }
    __syncthreads();
    for (int i = t; i < nc; i += 256) {
        int v = hh[i];
        h[(size_t)i * HP + b] = v;
        if (v) atomicAdd(&coltot[i], v);
    }
}

// ---- K2: binscatter (blocks [0,nblk)) || gemm (blocks [nblk,...)) -------
// binscatter self-computes its bases (LDS coltot scan + int4 prefix over own
// h-row slice); its latency hides under the gemm blocks in the same launch.

__global__ __launch_bounds__(256) void binscatter_gemm(const int* __restrict__ src,
        const int* __restrict__ dst, const int* __restrict__ h,
        const int* __restrict__ coltot, unsigned* __restrict__ ebuf,
        const float* __restrict__ x, const ushort* __restrict__ Wp,
        ushort* __restrict__ xwq, int E, int N, int nc, int nblk) {
    __shared__ alignas(16) ushort Wlds[16384];   // 32 KB
    int t = threadIdx.x, b = blockIdx.x;

    if (b < nblk) {
        // ---------------- binscatter ----------------
        int* smc = (int*)Wlds;          // [256]
        int* cur = smc + 256;           // [NCMAX]
        smc[t] = (t < nc) ? coltot[t] : 0;        // inclusive scan of coltot
        __syncthreads();
        #pragma unroll
        for (int d = 1; d < 256; d <<= 1) {
            int u = (t >= d) ? smc[t - d] : 0;
            __syncthreads();
            smc[t] += u;
            __syncthreads();
        }
        if (t < nc) {
            int base = (t > 0) ? smc[t - 1] : 0;  // exclusive bucket base
            const int* hp = &h[(size_t)t * HP];
            int pfx = 0;
            int j = 0;
            for (; j + 4 <= b; j += 4) {          // 16B-aligned int4 (HP=256)
                int4 v = *(const int4*)&hp[j];
                pfx += v.x + v.y + v.z + v.w;
            }
            for (; j < b; ++j) pfx += hp[j];
            cur[t] = base + pfx;
        }
        __syncthreads();
        int s = b * CHUNK, e = min(E, s + CHUNK);
        for (int i = s + t; i < e; i += 256) {
            int d = dst[i];
            int pos = atomicAdd(&cur[d >> 8], 1);
            ebuf[pos] = (unsigned)src[i] | ((unsigned)(d & 255) << 16);
        }
        return;
    }

    // ---- gemm: xwq[q][r][32] = bf16((x[r] @ W)[q*32..]) (no dinv) ----
    int gb = b - nblk;
    int wv = t >> 6, l = t & 63;
    int c15 = l & 15, kc = l >> 4;               // kc in 0..3
    int row0 = gb * 64 + wv * 16;
    int r = row0 + c15;
    bool valid = r < N;

    short8 af[4];
    #pragma unroll
    for (int ks = 0; ks < 4; ++ks) {
        float4 a0 = make_float4(0.f,0.f,0.f,0.f), a1 = a0;
        if (valid) {
            const float* p = x + (size_t)r * CH + ks * 32 + kc * 8;
            a0 = *(const float4*)p;
            a1 = *(const float4*)(p + 4);
        }
        short8 v;
        v[0]=f2bf(a0.x); v[1]=f2bf(a0.y); v[2]=f2bf(a0.z); v[3]=f2bf(a0.w);
        v[4]=f2bf(a1.x); v[5]=f2bf(a1.y); v[6]=f2bf(a1.z); v[7]=f2bf(a1.w);
        af[ks] = v;
    }

    #pragma unroll
    for (int i = 0; i < 8; ++i) {
        int idx = i * 256 + t;
        *(uint4*)&Wlds[idx * 8] = *(const uint4*)&Wp[idx * 8];
    }
    __syncthreads();

    f32x4 acc[8];
    #pragma unroll
    for (int ct = 0; ct < 8; ++ct) { f32x4 z = {0.f,0.f,0.f,0.f}; acc[ct] = z; }

    int swz = l & 7;
    #pragma unroll
    for (int ks = 0; ks < 4; ++ks) {
        #pragma unroll
        for (int ct = 0; ct < 8; ++ct) {
            int col = ct * 16 + c15;
            int idx16 = (col * 16 + ks * 4 + kc) ^ swz;
            short8 bfrag = *(const short8*)&Wlds[idx16 * 8];
            acc[ct] = __builtin_amdgcn_mfma_f32_16x16x32_bf16(af[ks], bfrag, acc[ct], 0, 0, 0);
        }
    }
    __syncthreads();   // all waves done reading Wlds; reuse as bounce buffer

    ushort* bw = Wlds + wv * 2048;   // 16 rows x 128 cols bf16 per wave
    #pragma unroll
    for (int ct = 0; ct < 8; ++ct) {
        #pragma unroll
        for (int rr = 0; rr < 4; ++rr) {
            int row_local = kc * 4 + rr;
            bw[row_local * CH + ct * 16 + c15] = f2bf(acc[ct][rr]);
        }
    }
    // quartered store: quarter q = c15>>2, 32 ch per quarter, 16B per lane
    int q = c15 >> 2;
    #pragma unroll
    for (int p = 0; p < 4; ++p) {
        int row_local = p * 4 + kc;
        int row = row0 + row_local;
        if (row < N) {
            uint4 vv = *(const uint4*)&bw[row_local * CH + c15 * 8];
            *(uint4*)&xwq[((size_t)q * N + row) * 32 + (c15 & 3) * 8] = vv;
        }
    }
}

// ---- K3: per-bucket CSR build -> off/dinv/csr (s,e from coltot scan) ----

__global__ __launch_bounds__(256) void bucket_csr(const unsigned* __restrict__ ebuf,
        const int* __restrict__ coltot, int* __restrict__ off, ushort* __restrict__ csr,
        float* __restrict__ dinv, int N, int nc) {
    __shared__ int hist2[256], cur[256], sm[256];
    int t = threadIdx.x, k = blockIdx.x;
    sm[t] = (t < nc) ? coltot[t] : 0;         // inclusive scan of coltot
    __syncthreads();
    #pragma unroll
    for (int d = 1; d < 256; d <<= 1) {
        int u = (t >= d) ? sm[t - d] : 0;
        __syncthreads();
        sm[t] += u;
        __syncthreads();
    }
    int s = (k > 0) ? sm[k - 1] : 0;          // broadcast reads
    int e = sm[k];
    __syncthreads();

    hist2[t] = 0;
    __syncthreads();
    for (int i = s + t; i < e; i += 256) atomicAdd(&hist2[(ebuf[i] >> 16) & 255], 1);
    __syncthreads();
    int v = hist2[t];
    sm[t] = v;
    __syncthreads();
    #pragma unroll
    for (int d = 1; d < 256; d <<= 1) {
        int u = (t >= d) ? sm[t - d] : 0;
        __syncthreads();
        sm[t] += u;
        __syncthreads();
    }
    int excl = sm[t] - v;
    int node = k * 256 + t;
    if (node <= N) off[node] = s + excl;
    if (node < N) dinv[node] = rsqrtf((float)(v + 1));   // +1 self loop
    cur[t] = s + excl;
    __syncthreads();
    for (int i = s + t; i < e; i += 256) {
        unsigned u = ebuf[i];
        int pos = atomicAdd(&cur[(u >> 16) & 255], 1);
        csr[pos] = (ushort)(u & 0xffffu);
    }
}

// ---- K4: out[i] = di*(sum_j dinv_j*xw_j + di*xw_i) + b ------------------
// Quartered (4 lanes/node, q=(bid&7)>>1 -> one 3.2MB quarter per XCD pair);
// masked unroll-8 with dinv[src] AS the mask multiplier; nontemporal out.

__global__ __launch_bounds__(256) void agg_kernel(const ushort* __restrict__ xwq,
        const ushort* __restrict__ csr, const int* __restrict__ off,
        const float* __restrict__ dinv, const float* __restrict__ b,
        float* __restrict__ out, int N) {
    int t = threadIdx.x;
    int bid = blockIdx.x;
    int q = (bid & 7) >> 1;                   // quarter (XCD pair)
    int iw = (bid >> 3) * 2 + (bid & 1);      // node-block within quarter
    int node = iw * 64 + (t >> 2);
    if (node >= N) return;
    int lane4 = t & 3;                        // 8 ch per lane within quarter
    int s = off[node], e = off[node + 1];
    float acc[8] = {0.f,0.f,0.f,0.f,0.f,0.f,0.f,0.f};
    const ushort* base = xwq + (size_t)q * N * 32 + lane4 * 8;
    float di = dinv[node];

    int last = e - 1;
    for (int j = s; j < e; j += 8) {
        int idx[8]; float m[8];
        #pragma unroll
        for (int k = 0; k < 8; ++k) {
            int jj = j + k;
            idx[k] = csr[min(jj, last)];
            m[k] = (jj <= last) ? dinv[idx[k]] : 0.0f;   // weight = dinv[src]
        }
        uint4 v[8];
        #pragma unroll
        for (int k = 0; k < 8; ++k)
            v[k] = *(const uint4*)(base + (size_t)idx[k] * 32);
        #pragma unroll
        for (int k = 0; k < 8; ++k) {
            acc[0] += m[k] * __uint_as_float(v[k].x << 16);
            acc[1] += m[k] * __uint_as_float(v[k].x & 0xffff0000u);
            acc[2] += m[k] * __uint_as_float(v[k].y << 16);
            acc[3] += m[k] * __uint_as_float(v[k].y & 0xffff0000u);
            acc[4] += m[k] * __uint_as_float(v[k].z << 16);
            acc[5] += m[k] * __uint_as_float(v[k].z & 0xffff0000u);
            acc[6] += m[k] * __uint_as_float(v[k].w << 16);
            acc[7] += m[k] * __uint_as_float(v[k].w & 0xffff0000u);
        }
    }
    {   // self loop term: weight di (outer di gives di^2)
        uint4 v = *(const uint4*)(base + (size_t)node * 32);
        acc[0] += di * __uint_as_float(v.x << 16);
        acc[1] += di * __uint_as_float(v.x & 0xffff0000u);
        acc[2] += di * __uint_as_float(v.y << 16);
        acc[3] += di * __uint_as_float(v.y & 0xffff0000u);
        acc[4] += di * __uint_as_float(v.z << 16);
        acc[5] += di * __uint_as_float(v.z & 0xffff0000u);
        acc[6] += di * __uint_as_float(v.w << 16);
        acc[7] += di * __uint_as_float(v.w & 0xffff0000u);
    }
    int ch0 = q * 32 + lane4 * 8;
    float4 b0 = *(const float4*)&b[ch0];
    float4 b1 = *(const float4*)&b[ch0 + 4];
    f32x4 o0, o1;
    o0[0] = di * acc[0] + b0.x;  o0[1] = di * acc[1] + b0.y;
    o0[2] = di * acc[2] + b0.z;  o0[3] = di * acc[3] + b0.w;
    o1[0] = di * acc[4] + b1.x;  o1[1] = di * acc[5] + b1.y;
    o1[2] = di * acc[6] + b1.z;  o1[3] = di * acc[7] + b1.w;
    float* op = out + (size_t)node * CH + ch0;
    __builtin_nontemporal_store(o0, (f32x4*)op);
    __builtin_nontemporal_store(o1, (f32x4*)(op + 4));
}

// ---- launch -------------------------------------------------------------

extern "C" void kernel_launch(void* const* d_in, const int* in_sizes, int n_in,
                              void* d_out, int out_size, void* d_ws, size_t ws_size,
                              hipStream_t stream) {
    const float* x  = (const float*)d_in[0];
    const float* Wm = (const float*)d_in[1];
    const float* b  = (const float*)d_in[2];
    const int*   ei = (const int*)d_in[3];
    int N = in_sizes[0] / CH;
    int E = in_sizes[3] / 2;
    const int* src = ei;
    const int* dst = ei + E;
    float* out = (float*)d_out;

    char* w = (char*)d_ws;
    auto alloc = [&](size_t bytes) {
        char* p = w;
        w += (bytes + 255) & ~(size_t)255;
        return p;
    };
    int nc = (N + 255) >> 8;                     // 196 coarse buckets
    int nblk = (E + CHUNK - 1) / CHUNK;          // 196 binning blocks
    int gemm_blocks = (N + 63) / 64;             // 782

    ushort*   xwq  = (ushort*)alloc((size_t)N * CH * 2);   // 4 x 3.2 MB quarters
    unsigned* ebuf = (unsigned*)alloc((size_t)E * 4);      // 3.2 MB (NOT aliased)
    int*      off  = (int*)alloc((size_t)(N + 1) * 4);
    ushort*   csr  = (ushort*)alloc((size_t)E * 2);
    float*    dinv = (float*)alloc((size_t)N * 4);
    ushort*   Wp   = (ushort*)alloc((size_t)16384 * 2);
    int*      h    = (int*)alloc((size_t)nc * HP * 4);     // 200 KB (pitch 256)
    int*      coltot=(int*)alloc((size_t)nc * 4);

    (void)hipMemsetAsync(coltot, 0, (size_t)nc * 4, stream);   // 784 B, capture-safe
    hist_packw<<<nblk + 8, 256, 0, stream>>>(dst, h, coltot, Wm, Wp, E, nc, nblk);
    binscatter_gemm<<<nblk + gemm_blocks, 256, 0, stream>>>(src, dst, h, coltot, ebuf,
                                                            x, Wp, xwq, E, N, nc, nblk);
    bucket_csr<<<nc, 256, 0, stream>>>(ebuf, coltot, off, csr, dinv, N, nc);
    int nbq = (N + 63) / 64;                     // node-blocks per quarter
    int agg_grid = ((nbq + 1) / 2) * 8;          // 4 quarters x 2 XCDs each
    agg_kernel<<<agg_grid, 256, 0, stream>>>(xwq, csr, off, dinv, b, out, N);
}

// Round 17
// 89.269 us; speedup vs baseline: 1.0150x; 1.0150x over previous
//
#include <hip/hip_runtime.h>

// GCN layer: out = D^-1/2 (A + I) D^-1/2 (X W) + b
// N=50000, E=800000, 128 ch. MFMA bf16 GEMM + fused dinv scaling + bf16
// XCD-quartered gather table (3.2MB/quarter -> per-XCD-pair L2 resident).
// History: R3 counting-sort CSR; R6 masked unroll-8 agg; R7 FAILED barriers;
// R8 FAILED fold race; R9 triangular colscan; R11 82.3; R12 ILP/TLP lesson;
// R15 quartered table 81.1 (best); R16 REGRESSED 90.6 -- dinv-at-agg added a
// dependent random load per gather (agg 43.7us measured), quartering itself
// verified good (FETCH 81->19MB).
// R17: R15 + degree-sorted node permutation (computed free in bucket_csr via
//      LDS counting-sort) -- agg waves process equal-degree nodes, killing the
//      ~1.9x lockstep divergence of Poisson(16) degrees.

constexpr int CH = 128;
constexpr int CHUNK = 4096;    // edges per binning block
constexpr int NCMAX = 256;     // max coarse buckets (256 nodes each -> N <= 65536)

typedef __attribute__((ext_vector_type(8))) short short8;
typedef __attribute__((ext_vector_type(4))) float f32x4;

static __device__ __forceinline__ ushort f2bf(float f) {
    unsigned u = __float_as_uint(f);
    u += 0x7fff + ((u >> 16) & 1);   // RNE
    return (ushort)(u >> 16);
}

// ---- CSR build: counting sort by destination ----------------------------
// h layout: h[bucket * nblk + block]  (transposed -> colscan coalesced)

__global__ __launch_bounds__(256) void hist_kernel(const int* __restrict__ dst,
        int* __restrict__ h, int* __restrict__ coltot, int E, int nc, int nblk) {
    __shared__ int hh[NCMAX];
    int t = threadIdx.x, b = blockIdx.x;
    for (int i = t; i < NCMAX; i += 256) hh[i] = 0;
    __syncthreads();
    int s = b * CHUNK, e = min(E, s + CHUNK);
    for (int i = s + t * 4; i < e; i += 1024) {
        if (i + 4 <= e) {
            int4 v = *(const int4*)&dst[i];
            atomicAdd(&hh[v.x >> 8], 1);
            atomicAdd(&hh[v.y >> 8], 1);
            atomicAdd(&hh[v.z >> 8], 1);
            atomicAdd(&hh[v.w >> 8], 1);
        } else {
            for (int k = i; k < e; ++k) atomicAdd(&hh[dst[k] >> 8], 1);
        }
    }
    __syncthreads();
    for (int i = t; i < nc; i += 256) {
        int v = hh[i];
        h[(size_t)i * nblk + b] = v;
        if (v) atomicAdd(&coltot[i], v);
    }
}

// block i: bbase_i = reduce(coltot[0..i)) in one parallel round; scan own
// column; write folded global bases in place (own column only -> race-free).
__global__ __launch_bounds__(256) void colscan_cols(int* __restrict__ h,
        const int* __restrict__ coltot, int* __restrict__ bbase, int nblk, int nc) {
    __shared__ int sm[256];
    int i = blockIdx.x, t = threadIdx.x;

    sm[t] = (t < i) ? coltot[t] : 0;    // nc <= 256: one round
    __syncthreads();
    #pragma unroll
    for (int d = 128; d > 0; d >>= 1) {
        if (t < d) sm[t] += sm[t + d];
        __syncthreads();
    }
    int bbase_i = sm[0];
    __syncthreads();

    int v = (t < nblk) ? h[(size_t)i * nblk + t] : 0;
    sm[t] = v;
    __syncthreads();
    #pragma unroll
    for (int d = 1; d < 256; d <<= 1) {
        int u = (t >= d) ? sm[t - d] : 0;
        __syncthreads();
        sm[t] += u;
        __syncthreads();
    }
    if (t < nblk) h[(size_t)i * nblk + t] = sm[t] - v + bbase_i;
    if (t == 0) {
        bbase[i] = bbase_i;
        if (i == nc - 1) bbase[nc] = bbase_i + coltot[i];   // == E
    }
}

// scatter packed (src | (dst&255)<<16) into bucket-sorted ebuf
__global__ __launch_bounds__(256) void binscatter_kernel(const int* __restrict__ src,
        const int* __restrict__ dst, const int* __restrict__ h,
        unsigned* __restrict__ ebuf, int E, int nc, int nblk) {
    __shared__ int cur[NCMAX];
    int t = threadIdx.x, b = blockIdx.x;
    for (int i = t; i < nc; i += 256) cur[i] = h[(size_t)i * nblk + b];
    __syncthreads();
    int s = b * CHUNK, e = min(E, s + CHUNK);
    for (int i = s + t; i < e; i += 256) {
        int d = dst[i];
        int pos = atomicAdd(&cur[d >> 8], 1);
        ebuf[pos] = (unsigned)src[i] | ((unsigned)(d & 255) << 16);
    }
}

// blocks [0,nc): per-bucket histogram + scan -> off/dinv, scatter src (ushort),
// then degree-sorted node permutation (LDS counting-sort by min(deg,255)).
// blocks [nc,nc+8): pack W fp32[128][128] -> bf16 transposed XOR-swizzled
__global__ __launch_bounds__(256) void bucket_csr_packw(const unsigned* __restrict__ ebuf,
        const int* __restrict__ bbase, int* __restrict__ off, ushort* __restrict__ csr,
        float* __restrict__ dinv, ushort* __restrict__ perm,
        const float* __restrict__ Wm, ushort* __restrict__ Wp,
        int N, int nc) {
    __shared__ int hist2[256], cur[256], sm[256];
    int t = threadIdx.x, k = blockIdx.x;
    if (k >= nc) {
        int tid = (k - nc) * 256 + t;   // 0..2047
        if (tid < 2048) {
            int col = tid >> 4, ch16 = tid & 15;
            ushort tmp[8];
            #pragma unroll
            for (int i = 0; i < 8; ++i)
                tmp[i] = f2bf(Wm[(size_t)(ch16 * 8 + i) * CH + col]);
            int d = col * 16 + (ch16 ^ (col & 7));
            *(uint4*)&Wp[(size_t)d * 8] = *(uint4*)tmp;
        }
        return;
    }
    int s = bbase[k], e = bbase[k + 1];
    hist2[t] = 0;
    __syncthreads();
    for (int i = s + t; i < e; i += 256) atomicAdd(&hist2[(ebuf[i] >> 16) & 255], 1);
    __syncthreads();
    int v = hist2[t];                  // degree of node k*256+t (kept in reg)
    sm[t] = v;
    __syncthreads();
    #pragma unroll
    for (int d = 1; d < 256; d <<= 1) {
        int u = (t >= d) ? sm[t - d] : 0;
        __syncthreads();
        sm[t] += u;
        __syncthreads();
    }
    int excl = sm[t] - v;
    int node = k * 256 + t;
    if (node <= N) off[node] = s + excl;
    if (node < N) dinv[node] = rsqrtf((float)(v + 1));   // +1 self loop
    cur[t] = s + excl;
    __syncthreads();
    for (int i = s + t; i < e; i += 256) {
        unsigned u = ebuf[i];
        int pos = atomicAdd(&cur[(u >> 16) & 255], 1);
        csr[pos] = (ushort)(u & 0xffffu);
    }
    __syncthreads();

    // ---- degree-sorted permutation within this bucket (counting sort) ----
    int key = min(v, 255);
    hist2[t] = 0;
    __syncthreads();
    if (node < N) atomicAdd(&hist2[key], 1);
    __syncthreads();
    int c = hist2[t];
    sm[t] = c;
    __syncthreads();
    #pragma unroll
    for (int d = 1; d < 256; d <<= 1) {
        int u = (t >= d) ? sm[t - d] : 0;
        __syncthreads();
        sm[t] += u;
        __syncthreads();
    }
    cur[t] = sm[t] - c;                // exclusive base per degree key
    __syncthreads();
    if (node < N) {
        int pos = atomicAdd(&cur[key], 1);
        perm[(size_t)k * 256 + pos] = (ushort)node;
    }
}

// ---- GEMM: xwq[q][r][32] = bf16((x[r] @ W)[q*32..] * dinv[r]) -----------

__global__ __launch_bounds__(256) void gemm_mfma(const float* __restrict__ x,
        const ushort* __restrict__ Wp, const float* __restrict__ dinv,
        ushort* __restrict__ xwq, int N) {
    __shared__ alignas(16) ushort Wlds[16384];   // 32 KB
    int t = threadIdx.x;
    int wv = t >> 6, l = t & 63;
    int c15 = l & 15, kc = l >> 4;               // kc in 0..3
    int row0 = blockIdx.x * 64 + wv * 16;
    int r = row0 + c15;
    bool valid = r < N;

    short8 af[4];
    #pragma unroll
    for (int ks = 0; ks < 4; ++ks) {
        float4 a0 = make_float4(0.f,0.f,0.f,0.f), a1 = a0;
        if (valid) {
            const float* p = x + (size_t)r * CH + ks * 32 + kc * 8;
            a0 = *(const float4*)p;
            a1 = *(const float4*)(p + 4);
        }
        short8 v;
        v[0]=f2bf(a0.x); v[1]=f2bf(a0.y); v[2]=f2bf(a0.z); v[3]=f2bf(a0.w);
        v[4]=f2bf(a1.x); v[5]=f2bf(a1.y); v[6]=f2bf(a1.z); v[7]=f2bf(a1.w);
        af[ks] = v;
    }

    #pragma unroll
    for (int i = 0; i < 8; ++i) {
        int idx = i * 256 + t;
        *(uint4*)&Wlds[idx * 8] = *(const uint4*)&Wp[idx * 8];
    }
    __syncthreads();

    f32x4 acc[8];
    #pragma unroll
    for (int ct = 0; ct < 8; ++ct) { f32x4 z = {0.f,0.f,0.f,0.f}; acc[ct] = z; }

    int swz = l & 7;
    #pragma unroll
    for (int ks = 0; ks < 4; ++ks) {
        #pragma unroll
        for (int ct = 0; ct < 8; ++ct) {
            int col = ct * 16 + c15;
            int idx16 = (col * 16 + ks * 4 + kc) ^ swz;
            short8 bfrag = *(const short8*)&Wlds[idx16 * 8];
            acc[ct] = __builtin_amdgcn_mfma_f32_16x16x32_bf16(af[ks], bfrag, acc[ct], 0, 0, 0);
        }
    }

    float dv[4];
    #pragma unroll
    for (int rr = 0; rr < 4; ++rr) {
        int row = row0 + kc * 4 + rr;
        dv[rr] = (row < N) ? dinv[row] : 0.f;
    }
    __syncthreads();   // all waves done reading Wlds; reuse as bounce buffer

    ushort* bw = Wlds + wv * 2048;   // 16 rows x 128 cols bf16 per wave
    #pragma unroll
    for (int ct = 0; ct < 8; ++ct) {
        #pragma unroll
        for (int rr = 0; rr < 4; ++rr) {
            int row_local = kc * 4 + rr;
            bw[row_local * CH + ct * 16 + c15] = f2bf(acc[ct][rr] * dv[rr]);
        }
    }
    // quartered store: quarter q = c15>>2, 32 ch per quarter, 16B per lane
    int q = c15 >> 2;
    #pragma unroll
    for (int p = 0; p < 4; ++p) {
        int row_local = p * 4 + kc;
        int row = row0 + row_local;
        if (row < N) {
            uint4 vv = *(const uint4*)&bw[row_local * CH + c15 * 8];
            *(uint4*)&xwq[((size_t)q * N + row) * 32 + (c15 & 3) * 8] = vv;
        }
    }
}

// ---- Aggregation: out[i] = dinv[i] * (sum_j xwq[src_j] + xwq[i]) + b ----
// 4 lanes/node, quarter q=(bid&7)>>1 (one 3.2MB quarter per XCD pair);
// nodes visited in degree-sorted perm order -> equal-degree waves, no
// lockstep divergence. Masked unroll-8, nontemporal out.

__global__ __launch_bounds__(256) void agg_kernel(const ushort* __restrict__ xwq,
        const ushort* __restrict__ csr, const int* __restrict__ off,
        const float* __restrict__ dinv, const float* __restrict__ b,
        const ushort* __restrict__ perm, float* __restrict__ out, int N) {
    int t = threadIdx.x;
    int bid = blockIdx.x;
    int q = (bid & 7) >> 1;                   // quarter (XCD pair)
    int iw = (bid >> 3) * 2 + (bid & 1);      // node-block within quarter
    int slot = iw * 64 + (t >> 2);
    if (slot >= N) return;
    int node = perm[slot];                    // degree-sorted visit order
    int lane4 = t & 3;                        // 8 ch per lane within quarter
    int s = off[node], e = off[node + 1];
    float acc[8] = {0.f,0.f,0.f,0.f,0.f,0.f,0.f,0.f};
    const ushort* base = xwq + (size_t)q * N * 32 + lane4 * 8;

    int last = e - 1;
    for (int j = s; j < e; j += 8) {
        int idx[8]; float m[8];
        #pragma unroll
        for (int k = 0; k < 8; ++k) {
            int jj = j + k;
            idx[k] = csr[min(jj, last)];
            m[k] = (jj <= last) ? 1.0f : 0.0f;
        }
        uint4 v[8];
        #pragma unroll
        for (int k = 0; k < 8; ++k)
            v[k] = *(const uint4*)(base + (size_t)idx[k] * 32);
        #pragma unroll
        for (int k = 0; k < 8; ++k) {
            acc[0] += m[k] * __uint_as_float(v[k].x << 16);
            acc[1] += m[k] * __uint_as_float(v[k].x & 0xffff0000u);
            acc[2] += m[k] * __uint_as_float(v[k].y << 16);
            acc[3] += m[k] * __uint_as_float(v[k].y & 0xffff0000u);
            acc[4] += m[k] * __uint_as_float(v[k].z << 16);
            acc[5] += m[k] * __uint_as_float(v[k].z & 0xffff0000u);
            acc[6] += m[k] * __uint_as_float(v[k].w << 16);
            acc[7] += m[k] * __uint_as_float(v[k].w & 0xffff0000u);
        }
    }
    {   // self loop term
        uint4 v = *(const uint4*)(base + (size_t)node * 32);
        acc[0] += __uint_as_float(v.x << 16);
        acc[1] += __uint_as_float(v.x & 0xffff0000u);
        acc[2] += __uint_as_float(v.y << 16);
        acc[3] += __uint_as_float(v.y & 0xffff0000u);
        acc[4] += __uint_as_float(v.z << 16);
        acc[5] += __uint_as_float(v.z & 0xffff0000u);
        acc[6] += __uint_as_float(v.w << 16);
        acc[7] += __uint_as_float(v.w & 0xffff0000u);
    }
    float di = dinv[node];
    int ch0 = q * 32 + lane4 * 8;
    float4 b0 = *(const float4*)&b[ch0];
    float4 b1 = *(const float4*)&b[ch0 + 4];
    f32x4 o0, o1;
    o0[0] = di * acc[0] + b0.x;  o0[1] = di * acc[1] + b0.y;
    o0[2] = di * acc[2] + b0.z;  o0[3] = di * acc[3] + b0.w;
    o1[0] = di * acc[4] + b1.x;  o1[1] = di * acc[5] + b1.y;
    o1[2] = di * acc[6] + b1.z;  o1[3] = di * acc[7] + b1.w;
    float* op = out + (size_t)node * CH + ch0;
    __builtin_nontemporal_store(o0, (f32x4*)op);
    __builtin_nontemporal_store(o1, (f32x4*)(op + 4));
}

// ---- launch -------------------------------------------------------------

extern "C" void kernel_launch(void* const* d_in, const int* in_sizes, int n_in,
                              void* d_out, int out_size, void* d_ws, size_t ws_size,
                              hipStream_t stream) {
    const float* x  = (const float*)d_in[0];
    const float* Wm = (const float*)d_in[1];
    const float* b  = (const float*)d_in[2];
    const int*   ei = (const int*)d_in[3];
    int N = in_sizes[0] / CH;
    int E = in_sizes[3] / 2;
    const int* src = ei;
    const int* dst = ei + E;
    float* out = (float*)d_out;

    char* w = (char*)d_ws;
    auto alloc = [&](size_t bytes) {
        char* p = w;
        w += (bytes + 255) & ~(size_t)255;
        return p;
    };
    int nc = (N + 255) >> 8;                     // 196 coarse buckets
    int nblk = (E + CHUNK - 1) / CHUNK;          // 196 binning blocks

    ushort*   xwq  = (ushort*)alloc((size_t)N * CH * 2);   // 4 x 3.2 MB quarters
    unsigned* ebuf = (unsigned*)xwq;                       // E*4 = 3.2 MB, dead before gemm
    int*      off  = (int*)alloc((size_t)(N + 1) * 4);
    ushort*   csr  = (ushort*)alloc((size_t)E * 2);
    float*    dinv = (float*)alloc((size_t)N * 4);
    ushort*   Wp   = (ushort*)alloc((size_t)16384 * 2);
    int*      h    = (int*)alloc((size_t)nc * nblk * 4);   // 154 KB
    int*      bbase= (int*)alloc((size_t)(nc + 1) * 4);
    int*      coltot=(int*)alloc((size_t)nc * 4);
    ushort*   perm = (ushort*)alloc((size_t)nc * 256 * 2); // 100 KB

    (void)hipMemsetAsync(coltot, 0, (size_t)nc * 4, stream);   // 784 B, capture-safe
    hist_kernel<<<nblk, 256, 0, stream>>>(dst, h, coltot, E, nc, nblk);
    colscan_cols<<<nc, 256, 0, stream>>>(h, coltot, bbase, nblk, nc);
    binscatter_kernel<<<nblk, 256, 0, stream>>>(src, dst, h, ebuf, E, nc, nblk);
    bucket_csr_packw<<<nc + 8, 256, 0, stream>>>(ebuf, bbase, off, csr, dinv, perm,
                                                 Wm, Wp, N, nc);
    gemm_mfma<<<(N + 63) / 64, 256, 0, stream>>>(x, Wp, dinv, xwq, N);
    int nbq = (N + 63) / 64;                     // node-blocks per quarter
    int agg_grid = ((nbq + 1) / 2) * 8;          // 4 quarters x 2 XCDs each
    agg_kernel<<<agg_grid, 256, 0, stream>>>(xwq, csr, off, dinv, b, perm, out, N);
}

// Round 18
// 82.119 us; speedup vs baseline: 1.1034x; 1.0871x over previous
//
#include <hip/hip_runtime.h>

// GCN layer: out = D^-1/2 (A + I) D^-1/2 (X W) + b
// N=50000, E=800000, 128 ch. MFMA bf16 GEMM + bf16 XCD-quartered gather table.
// Evidence: quartering good (R16: FETCH 81->19MB); dinv MUST be prefolded
// (R16: dinv-at-agg doubled gather latency, agg 43.7us); binscatter||gemm
// overlap worth ~5us (R16 K2); degree-perm scatters out-writes (R17 regress).
// R18: overlap pipeline + in-bucket table scaling:
//   K1[hist || packw] -> K2[binscatter(self-bases) || gemm (dinv-free)] ->
//   K3[bucket_csr: dinv + csr + SCALE own 64KB xwq slice] -> K4[agg = R15's].

constexpr int CH = 128;
constexpr int CHUNK = 4096;    // edges per binning block
constexpr int NCMAX = 256;     // max coarse buckets (256 nodes each -> N <= 65536)
constexpr int HP = 256;        // h row pitch (ints) -> 16B-aligned int4 rows

typedef __attribute__((ext_vector_type(8))) short short8;
typedef __attribute__((ext_vector_type(4))) float f32x4;

static __device__ __forceinline__ ushort f2bf(float f) {
    unsigned u = __float_as_uint(f);
    u += 0x7fff + ((u >> 16) & 1);   // RNE
    return (ushort)(u >> 16);
}

// ---- K1: hist (blocks [0,nblk)) || pack_w (blocks [nblk,nblk+8)) --------

__global__ __launch_bounds__(256) void hist_packw(const int* __restrict__ dst,
        int* __restrict__ h, int* __restrict__ coltot,
        const float* __restrict__ Wm, ushort* __restrict__ Wp,
        int E, int nc, int nblk) {
    int t = threadIdx.x, b = blockIdx.x;
    if (b >= nblk) {
        int tid = (b - nblk) * 256 + t;   // 0..2047
        if (tid < 2048) {
            int col = tid >> 4, ch16 = tid & 15;
            ushort tmp[8];
            #pragma unroll
            for (int i = 0; i < 8; ++i)
                tmp[i] = f2bf(Wm[(size_t)(ch16 * 8 + i) * CH + col]);
            int d = col * 16 + (ch16 ^ (col & 7));
            *(uint4*)&Wp[(size_t)d * 8] = *(uint4*)tmp;
        }
        return;
    }
    __shared__ int hh[NCMAX];
    for (int i = t; i < NCMAX; i += 256) hh[i] = 0;
    __syncthreads();
    int s = b * CHUNK, e = min(E, s + CHUNK);
    for (int i = s + t * 4; i < e; i += 1024) {
        if (i + 4 <= e) {
            int4 v = *(const int4*)&dst[i];
            atomicAdd(&hh[v.x >> 8], 1);
            atomicAdd(&hh[v.y >> 8], 1);
            atomicAdd(&hh[v.z >> 8], 1);
            atomicAdd(&hh[v.w >> 8], 1);
        } else {
            for (int k = i; k < e; ++k) atomicAdd(&hh[dst[k] >> 8], 1);
        }
    }
    __syncthreads();
    for (int i = t; i < nc; i += 256) {
        int v = hh[i];
        h[(size_t)i * HP + b] = v;
        if (v) atomicAdd(&coltot[i], v);
    }
}

// ---- K2: binscatter (blocks [0,nblk)) || gemm (blocks [nblk,...)) -------
// binscatter self-computes bases (LDS coltot scan + int4 prefix over own
// h-row slice); its latency hides under the gemm blocks in the same launch.

__global__ __launch_bounds__(256) void binscatter_gemm(const int* __restrict__ src,
        const int* __restrict__ dst, const int* __restrict__ h,
        const int* __restrict__ coltot, unsigned* __restrict__ ebuf,
        const float* __restrict__ x, const ushort* __restrict__ Wp,
        ushort* __restrict__ xwq, int E, int N, int nc, int nblk) {
    __shared__ alignas(16) ushort Wlds[16384];   // 32 KB
    int t = threadIdx.x, b = blockIdx.x;

    if (b < nblk) {
        // ---------------- binscatter ----------------
        int* smc = (int*)Wlds;          // [256]
        int* cur = smc + 256;           // [NCMAX]
        smc[t] = (t < nc) ? coltot[t] : 0;        // inclusive scan of coltot
        __syncthreads();
        #pragma unroll
        for (int d = 1; d < 256; d <<= 1) {
            int u = (t >= d) ? smc[t - d] : 0;
            __syncthreads();
            smc[t] += u;
            __syncthreads();
        }
        if (t < nc) {
            int base = (t > 0) ? smc[t - 1] : 0;  // exclusive bucket base
            const int* hp = &h[(size_t)t * HP];
            int pfx = 0;
            int j = 0;
            for (; j + 4 <= b; j += 4) {          // 16B-aligned int4 (HP=256)
                int4 v = *(const int4*)&hp[j];
                pfx += v.x + v.y + v.z + v.w;
            }
            for (; j < b; ++j) pfx += hp[j];
            cur[t] = base + pfx;
        }
        __syncthreads();
        int s = b * CHUNK, e = min(E, s + CHUNK);
        for (int i = s + t; i < e; i += 256) {
            int d = dst[i];
            int pos = atomicAdd(&cur[d >> 8], 1);
            ebuf[pos] = (unsigned)src[i] | ((unsigned)(d & 255) << 16);
        }
        return;
    }

    // ---- gemm: xwq[q][r][32] = bf16((x[r] @ W)[q*32..]) (no dinv) ----
    int gb = b - nblk;
    int wv = t >> 6, l = t & 63;
    int c15 = l & 15, kc = l >> 4;               // kc in 0..3
    int row0 = gb * 64 + wv * 16;
    int r = row0 + c15;
    bool valid = r < N;

    short8 af[4];
    #pragma unroll
    for (int ks = 0; ks < 4; ++ks) {
        float4 a0 = make_float4(0.f,0.f,0.f,0.f), a1 = a0;
        if (valid) {
            const float* p = x + (size_t)r * CH + ks * 32 + kc * 8;
            a0 = *(const float4*)p;
            a1 = *(const float4*)(p + 4);
        }
        short8 v;
        v[0]=f2bf(a0.x); v[1]=f2bf(a0.y); v[2]=f2bf(a0.z); v[3]=f2bf(a0.w);
        v[4]=f2bf(a1.x); v[5]=f2bf(a1.y); v[6]=f2bf(a1.z); v[7]=f2bf(a1.w);
        af[ks] = v;
    }

    #pragma unroll
    for (int i = 0; i < 8; ++i) {
        int idx = i * 256 + t;
        *(uint4*)&Wlds[idx * 8] = *(const uint4*)&Wp[idx * 8];
    }
    __syncthreads();

    f32x4 acc[8];
    #pragma unroll
    for (int ct = 0; ct < 8; ++ct) { f32x4 z = {0.f,0.f,0.f,0.f}; acc[ct] = z; }

    int swz = l & 7;
    #pragma unroll
    for (int ks = 0; ks < 4; ++ks) {
        #pragma unroll
        for (int ct = 0; ct < 8; ++ct) {
            int col = ct * 16 + c15;
            int idx16 = (col * 16 + ks * 4 + kc) ^ swz;
            short8 bfrag = *(const short8*)&Wlds[idx16 * 8];
            acc[ct] = __builtin_amdgcn_mfma_f32_16x16x32_bf16(af[ks], bfrag, acc[ct], 0, 0, 0);
        }
    }
    __syncthreads();   // all waves done reading Wlds; reuse as bounce buffer

    ushort* bw = Wlds + wv * 2048;   // 16 rows x 128 cols bf16 per wave
    #pragma unroll
    for (int ct = 0; ct < 8; ++ct) {
        #pragma unroll
        for (int rr = 0; rr < 4; ++rr) {
            int row_local = kc * 4 + rr;
            bw[row_local * CH + ct * 16 + c15] = f2bf(acc[ct][rr]);
        }
    }
    // quartered store: quarter q = c15>>2, 32 ch per quarter, 16B per lane
    int q = c15 >> 2;
    #pragma unroll
    for (int p = 0; p < 4; ++p) {
        int row_local = p * 4 + kc;
        int row = row0 + row_local;
        if (row < N) {
            uint4 vv = *(const uint4*)&bw[row_local * CH + c15 * 8];
            *(uint4*)&xwq[((size_t)q * N + row) * 32 + (c15 & 3) * 8] = vv;
        }
    }
}

// ---- K3: per-bucket CSR build + dinv + scale own xwq slice --------------
// Block k: histogram+scan -> off/dinv/csr for nodes [k*256,(k+1)*256); then
// multiply xwq rows of those nodes by dinv (coalesced, 64KB/block, gemm done).

__global__ __launch_bounds__(256) void bucket_csr_scale(const unsigned* __restrict__ ebuf,
        const int* __restrict__ coltot, int* __restrict__ off, ushort* __restrict__ csr,
        float* __restrict__ dinv, ushort* __restrict__ xwq, int N, int nc) {
    __shared__ int hist2[256], cur[256], sm[256];
    __shared__ float dvs[256];
    int t = threadIdx.x, k = blockIdx.x;
    sm[t] = (t < nc) ? coltot[t] : 0;         // inclusive scan of coltot
    __syncthreads();
    #pragma unroll
    for (int d = 1; d < 256; d <<= 1) {
        int u = (t >= d) ? sm[t - d] : 0;
        __syncthreads();
        sm[t] += u;
        __syncthreads();
    }
    int s = (k > 0) ? sm[k - 1] : 0;          // broadcast reads
    int e = sm[k];
    __syncthreads();

    hist2[t] = 0;
    __syncthreads();
    for (int i = s + t; i < e; i += 256) atomicAdd(&hist2[(ebuf[i] >> 16) & 255], 1);
    __syncthreads();
    int v = hist2[t];
    sm[t] = v;
    __syncthreads();
    #pragma unroll
    for (int d = 1; d < 256; d <<= 1) {
        int u = (t >= d) ? sm[t - d] : 0;
        __syncthreads();
        sm[t] += u;
        __syncthreads();
    }
    int excl = sm[t] - v;
    int node = k * 256 + t;
    float dv = rsqrtf((float)(v + 1));        // +1 self loop
    if (node <= N) off[node] = s + excl;
    if (node < N) dinv[node] = dv;
    dvs[t] = dv;
    cur[t] = s + excl;
    __syncthreads();
    for (int i = s + t; i < e; i += 256) {
        unsigned u = ebuf[i];
        int pos = atomicAdd(&cur[(u >> 16) & 255], 1);
        csr[pos] = (ushort)(u & 0xffffu);
    }
    __syncthreads();

    // ---- scale this bucket's xwq rows by dinv (4 quarters x 16KB) ----
    #pragma unroll
    for (int q = 0; q < 4; ++q) {
        ushort* baseq = xwq + ((size_t)q * N + k * 256) * 32;
        #pragma unroll
        for (int it = 0; it < 4; ++it) {
            int i = it * 256 + t;             // uint4 index in [0,1024)
            int nl = i >> 2;                  // node_local
            if (k * 256 + nl < N) {
                float dd = dvs[nl];
                uint4 vv = *(const uint4*)&baseq[i * 8];
                ushort o[8];
                o[0] = f2bf(dd * __uint_as_float(vv.x << 16));
                o[1] = f2bf(dd * __uint_as_float(vv.x & 0xffff0000u));
                o[2] = f2bf(dd * __uint_as_float(vv.y << 16));
                o[3] = f2bf(dd * __uint_as_float(vv.y & 0xffff0000u));
                o[4] = f2bf(dd * __uint_as_float(vv.z << 16));
                o[5] = f2bf(dd * __uint_as_float(vv.z & 0xffff0000u));
                o[6] = f2bf(dd * __uint_as_float(vv.w << 16));
                o[7] = f2bf(dd * __uint_as_float(vv.w & 0xffff0000u));
                *(uint4*)&baseq[i * 8] = *(uint4*)o;
            }
        }
    }
}

// ---- K4: out[i] = dinv[i] * (sum_j xwq[src_j] + xwq[i]) + b -------------
// R15's exact agg: 4 lanes/node, quarter q=(bid&7)>>1 (3.2MB/quarter L2-
// resident per XCD pair), masked unroll-8, nontemporal out.

__global__ __launch_bounds__(256) void agg_kernel(const ushort* __restrict__ xwq,
        const ushort* __restrict__ csr, const int* __restrict__ off,
        const float* __restrict__ dinv, const float* __restrict__ b,
        float* __restrict__ out, int N) {
    int t = threadIdx.x;
    int bid = blockIdx.x;
    int q = (bid & 7) >> 1;                   // quarter (XCD pair)
    int iw = (bid >> 3) * 2 + (bid & 1);      // node-block within quarter
    int node = iw * 64 + (t >> 2);
    if (node >= N) return;
    int lane4 = t & 3;                        // 8 ch per lane within quarter
    int s = off[node], e = off[node + 1];
    float acc[8] = {0.f,0.f,0.f,0.f,0.f,0.f,0.f,0.f};
    const ushort* base = xwq + (size_t)q * N * 32 + lane4 * 8;

    int last = e - 1;
    for (int j = s; j < e; j += 8) {
        int idx[8]; float m[8];
        #pragma unroll
        for (int k = 0; k < 8; ++k) {
            int jj = j + k;
            idx[k] = csr[min(jj, last)];
            m[k] = (jj <= last) ? 1.0f : 0.0f;
        }
        uint4 v[8];
        #pragma unroll
        for (int k = 0; k < 8; ++k)
            v[k] = *(const uint4*)(base + (size_t)idx[k] * 32);
        #pragma unroll
        for (int k = 0; k < 8; ++k) {
            acc[0] += m[k] * __uint_as_float(v[k].x << 16);
            acc[1] += m[k] * __uint_as_float(v[k].x & 0xffff0000u);
            acc[2] += m[k] * __uint_as_float(v[k].y << 16);
            acc[3] += m[k] * __uint_as_float(v[k].y & 0xffff0000u);
            acc[4] += m[k] * __uint_as_float(v[k].z << 16);
            acc[5] += m[k] * __uint_as_float(v[k].z & 0xffff0000u);
            acc[6] += m[k] * __uint_as_float(v[k].w << 16);
            acc[7] += m[k] * __uint_as_float(v[k].w & 0xffff0000u);
        }
    }
    {   // self loop term
        uint4 v = *(const uint4*)(base + (size_t)node * 32);
        acc[0] += __uint_as_float(v.x << 16);
        acc[1] += __uint_as_float(v.x & 0xffff0000u);
        acc[2] += __uint_as_float(v.y << 16);
        acc[3] += __uint_as_float(v.y & 0xffff0000u);
        acc[4] += __uint_as_float(v.z << 16);
        acc[5] += __uint_as_float(v.z & 0xffff0000u);
        acc[6] += __uint_as_float(v.w << 16);
        acc[7] += __uint_as_float(v.w & 0xffff0000u);
    }
    float di = dinv[node];
    int ch0 = q * 32 + lane4 * 8;
    float4 b0 = *(const float4*)&b[ch0];
    float4 b1 = *(const float4*)&b[ch0 + 4];
    f32x4 o0, o1;
    o0[0] = di * acc[0] + b0.x;  o0[1] = di * acc[1] + b0.y;
    o0[2] = di * acc[2] + b0.z;  o0[3] = di * acc[3] + b0.w;
    o1[0] = di * acc[4] + b1.x;  o1[1] = di * acc[5] + b1.y;
    o1[2] = di * acc[6] + b1.z;  o1[3] = di * acc[7] + b1.w;
    float* op = out + (size_t)node * CH + ch0;
    __builtin_nontemporal_store(o0, (f32x4*)op);
    __builtin_nontemporal_store(o1, (f32x4*)(op + 4));
}

// ---- launch -------------------------------------------------------------

extern "C" void kernel_launch(void* const* d_in, const int* in_sizes, int n_in,
                              void* d_out, int out_size, void* d_ws, size_t ws_size,
                              hipStream_t stream) {
    const float* x  = (const float*)d_in[0];
    const float* Wm = (const float*)d_in[1];
    const float* b  = (const float*)d_in[2];
    const int*   ei = (const int*)d_in[3];
    int N = in_sizes[0] / CH;
    int E = in_sizes[3] / 2;
    const int* src = ei;
    const int* dst = ei + E;
    float* out = (float*)d_out;

    char* w = (char*)d_ws;
    auto alloc = [&](size_t bytes) {
        char* p = w;
        w += (bytes + 255) & ~(size_t)255;
        return p;
    };
    int nc = (N + 255) >> 8;                     // 196 coarse buckets
    int nblk = (E + CHUNK - 1) / CHUNK;          // 196 binning blocks
    int gemm_blocks = (N + 63) / 64;             // 782

    ushort*   xwq  = (ushort*)alloc((size_t)N * CH * 2);   // 4 x 3.2 MB quarters
    unsigned* ebuf = (unsigned*)alloc((size_t)E * 4);      // 3.2 MB (NOT aliased)
    int*      off  = (int*)alloc((size_t)(N + 1) * 4);
    ushort*   csr  = (ushort*)alloc((size_t)E * 2);
    float*    dinv = (float*)alloc((size_t)N * 4);
    ushort*   Wp   = (ushort*)alloc((size_t)16384 * 2);
    int*      h    = (int*)alloc((size_t)nc * HP * 4);     // 200 KB (pitch 256)
    int*      coltot=(int*)alloc((size_t)nc * 4);

    (void)hipMemsetAsync(coltot, 0, (size_t)nc * 4, stream);   // 784 B, capture-safe
    hist_packw<<<nblk + 8, 256, 0, stream>>>(dst, h, coltot, Wm, Wp, E, nc, nblk);
    binscatter_gemm<<<nblk + gemm_blocks, 256, 0, stream>>>(src, dst, h, coltot, ebuf,
                                                            x, Wp, xwq, E, N, nc, nblk);
    bucket_csr_scale<<<nc, 256, 0, stream>>>(ebuf, coltot, off, csr, dinv, xwq, N, nc);
    int nbq = (N + 63) / 64;                     // node-blocks per quarter
    int agg_grid = ((nbq + 1) / 2) * 8;          // 4 quarters x 2 XCDs each
    agg_kernel<<<agg_grid, 256, 0, stream>>>(xwq, csr, off, dinv, b, out, N);
}

// Round 19
// 80.901 us; speedup vs baseline: 1.1200x; 1.0151x over previous
//
#include <hip/hip_runtime.h>

// GCN layer: out = D^-1/2 (A + I) D^-1/2 (X W) + b
// N=50000, E=800000, 128 ch. MFMA bf16 GEMM + fused dinv scaling + bf16
// XCD-quartered gather table (3.2MB/quarter -> per-XCD-pair L2 resident).
// FINAL (= R15, measured best 81.1us):
//   R3 counting-sort CSR; R4/R10 parallel colscan via coltot; R5 packed
//   ebuf/csr (ushort); R6 masked unroll-8 agg (MLP 8 incl tail); R11
//   nontemporal out stores; R15 XCD-quartered table (FETCH 81->19MB, R16).
// Rejected by measurement: grid-barrier fusion (R7, cross-XCD ~30us/barrier);
//   in-place fold (R8 race); unroll-16 / 128-row gemm (R12, ILP trades TLP
//   at saturation); dispatch-count cuts & overlap pipelines (R13/14/16/18,
//   flat -- latency-structural floor); dinv-at-agg (R16, 2x gather latency);
//   degree-sorted perm (R17, scattered out-writes).

constexpr int CH = 128;
constexpr int CHUNK = 4096;    // edges per binning block
constexpr int NCMAX = 256;     // max coarse buckets (256 nodes each -> N <= 65536)

typedef __attribute__((ext_vector_type(8))) short short8;
typedef __attribute__((ext_vector_type(4))) float f32x4;

static __device__ __forceinline__ ushort f2bf(float f) {
    unsigned u = __float_as_uint(f);
    u += 0x7fff + ((u >> 16) & 1);   // RNE
    return (ushort)(u >> 16);
}

// ---- CSR build: counting sort by destination ----------------------------
// h layout: h[bucket * nblk + block]  (transposed -> colscan coalesced)

__global__ __launch_bounds__(256) void hist_kernel(const int* __restrict__ dst,
        int* __restrict__ h, int* __restrict__ coltot, int E, int nc, int nblk) {
    __shared__ int hh[NCMAX];
    int t = threadIdx.x, b = blockIdx.x;
    for (int i = t; i < NCMAX; i += 256) hh[i] = 0;
    __syncthreads();
    int s = b * CHUNK, e = min(E, s + CHUNK);
    for (int i = s + t * 4; i < e; i += 1024) {
        if (i + 4 <= e) {
            int4 v = *(const int4*)&dst[i];
            atomicAdd(&hh[v.x >> 8], 1);
            atomicAdd(&hh[v.y >> 8], 1);
            atomicAdd(&hh[v.z >> 8], 1);
            atomicAdd(&hh[v.w >> 8], 1);
        } else {
            for (int k = i; k < e; ++k) atomicAdd(&hh[dst[k] >> 8], 1);
        }
    }
    __syncthreads();
    for (int i = t; i < nc; i += 256) {
        int v = hh[i];
        h[(size_t)i * nblk + b] = v;
        if (v) atomicAdd(&coltot[i], v);
    }
}

// block i: bbase_i = reduce(coltot[0..i)) in one parallel round; scan own
// column; write folded global bases in place (own column only -> race-free).
__global__ __launch_bounds__(256) void colscan_cols(int* __restrict__ h,
        const int* __restrict__ coltot, int* __restrict__ bbase, int nblk, int nc) {
    __shared__ int sm[256];
    int i = blockIdx.x, t = threadIdx.x;

    sm[t] = (t < i) ? coltot[t] : 0;    // nc <= 256: one round
    __syncthreads();
    #pragma unroll
    for (int d = 128; d > 0; d >>= 1) {
        if (t < d) sm[t] += sm[t + d];
        __syncthreads();
    }
    int bbase_i = sm[0];
    __syncthreads();

    int v = (t < nblk) ? h[(size_t)i * nblk + t] : 0;
    sm[t] = v;
    __syncthreads();
    #pragma unroll
    for (int d = 1; d < 256; d <<= 1) {
        int u = (t >= d) ? sm[t - d] : 0;
        __syncthreads();
        sm[t] += u;
        __syncthreads();
    }
    if (t < nblk) h[(size_t)i * nblk + t] = sm[t] - v + bbase_i;
    if (t == 0) {
        bbase[i] = bbase_i;
        if (i == nc - 1) bbase[nc] = bbase_i + coltot[i];   // == E
    }
}

// scatter packed (src | (dst&255)<<16) into bucket-sorted ebuf
__global__ __launch_bounds__(256) void binscatter_kernel(const int* __restrict__ src,
        const int* __restrict__ dst, const int* __restrict__ h,
        unsigned* __restrict__ ebuf, int E, int nc, int nblk) {
    __shared__ int cur[NCMAX];
    int t = threadIdx.x, b = blockIdx.x;
    for (int i = t; i < nc; i += 256) cur[i] = h[(size_t)i * nblk + b];
    __syncthreads();
    int s = b * CHUNK, e = min(E, s + CHUNK);
    for (int i = s + t; i < e; i += 256) {
        int d = dst[i];
        int pos = atomicAdd(&cur[d >> 8], 1);
        ebuf[pos] = (unsigned)src[i] | ((unsigned)(d & 255) << 16);
    }
}

// blocks [0,nc): per-bucket histogram + scan -> off/dinv, scatter src (ushort)
// blocks [nc,nc+8): pack W fp32[128][128] -> bf16 transposed XOR-swizzled
__global__ __launch_bounds__(256) void bucket_csr_packw(const unsigned* __restrict__ ebuf,
        const int* __restrict__ bbase, int* __restrict__ off, ushort* __restrict__ csr,
        float* __restrict__ dinv, const float* __restrict__ Wm, ushort* __restrict__ Wp,
        int N, int nc) {
    __shared__ int hist2[256], cur[256], sm[256];
    int t = threadIdx.x, k = blockIdx.x;
    if (k >= nc) {
        int tid = (k - nc) * 256 + t;   // 0..2047
        if (tid < 2048) {
            int col = tid >> 4, ch16 = tid & 15;
            ushort tmp[8];
            #pragma unroll
            for (int i = 0; i < 8; ++i)
                tmp[i] = f2bf(Wm[(size_t)(ch16 * 8 + i) * CH + col]);
            int d = col * 16 + (ch16 ^ (col & 7));
            *(uint4*)&Wp[(size_t)d * 8] = *(uint4*)tmp;
        }
        return;
    }
    int s = bbase[k], e = bbase[k + 1];
    hist2[t] = 0;
    __syncthreads();
    for (int i = s + t; i < e; i += 256) atomicAdd(&hist2[(ebuf[i] >> 16) & 255], 1);
    __syncthreads();
    int v = hist2[t];
    sm[t] = v;
    __syncthreads();
    #pragma unroll
    for (int d = 1; d < 256; d <<= 1) {
        int u = (t >= d) ? sm[t - d] : 0;
        __syncthreads();
        sm[t] += u;
        __syncthreads();
    }
    int excl = sm[t] - v;
    int node = k * 256 + t;
    if (node <= N) off[node] = s + excl;
    if (node < N) dinv[node] = rsqrtf((float)(v + 1));   // +1 self loop
    cur[t] = s + excl;
    __syncthreads();
    for (int i = s + t; i < e; i += 256) {
        unsigned u = ebuf[i];
        int pos = atomicAdd(&cur[(u >> 16) & 255], 1);
        csr[pos] = (ushort)(u & 0xffffu);
    }
}

// ---- GEMM: xwq[q][r][32] = bf16((x[r] @ W)[q*32..] * dinv[r]) -----------

__global__ __launch_bounds__(256) void gemm_mfma(const float* __restrict__ x,
        const ushort* __restrict__ Wp, const float* __restrict__ dinv,
        ushort* __restrict__ xwq, int N) {
    __shared__ alignas(16) ushort Wlds[16384];   // 32 KB
    int t = threadIdx.x;
    int wv = t >> 6, l = t & 63;
    int c15 = l & 15, kc = l >> 4;               // kc in 0..3
    int row0 = blockIdx.x * 64 + wv * 16;
    int r = row0 + c15;
    bool valid = r < N;

    short8 af[4];
    #pragma unroll
    for (int ks = 0; ks < 4; ++ks) {
        float4 a0 = make_float4(0.f,0.f,0.f,0.f), a1 = a0;
        if (valid) {
            const float* p = x + (size_t)r * CH + ks * 32 + kc * 8;
            a0 = *(const float4*)p;
            a1 = *(const float4*)(p + 4);
        }
        short8 v;
        v[0]=f2bf(a0.x); v[1]=f2bf(a0.y); v[2]=f2bf(a0.z); v[3]=f2bf(a0.w);
        v[4]=f2bf(a1.x); v[5]=f2bf(a1.y); v[6]=f2bf(a1.z); v[7]=f2bf(a1.w);
        af[ks] = v;
    }

    #pragma unroll
    for (int i = 0; i < 8; ++i) {
        int idx = i * 256 + t;
        *(uint4*)&Wlds[idx * 8] = *(const uint4*)&Wp[idx * 8];
    }
    __syncthreads();

    f32x4 acc[8];
    #pragma unroll
    for (int ct = 0; ct < 8; ++ct) { f32x4 z = {0.f,0.f,0.f,0.f}; acc[ct] = z; }

    int swz = l & 7;
    #pragma unroll
    for (int ks = 0; ks < 4; ++ks) {
        #pragma unroll
        for (int ct = 0; ct < 8; ++ct) {
            int col = ct * 16 + c15;
            int idx16 = (col * 16 + ks * 4 + kc) ^ swz;
            short8 bfrag = *(const short8*)&Wlds[idx16 * 8];
            acc[ct] = __builtin_amdgcn_mfma_f32_16x16x32_bf16(af[ks], bfrag, acc[ct], 0, 0, 0);
        }
    }

    float dv[4];
    #pragma unroll
    for (int rr = 0; rr < 4; ++rr) {
        int row = row0 + kc * 4 + rr;
        dv[rr] = (row < N) ? dinv[row] : 0.f;
    }
    __syncthreads();   // all waves done reading Wlds; reuse as bounce buffer

    ushort* bw = Wlds + wv * 2048;   // 16 rows x 128 cols bf16 per wave
    #pragma unroll
    for (int ct = 0; ct < 8; ++ct) {
        #pragma unroll
        for (int rr = 0; rr < 4; ++rr) {
            int row_local = kc * 4 + rr;
            bw[row_local * CH + ct * 16 + c15] = f2bf(acc[ct][rr] * dv[rr]);
        }
    }
    // quartered store: quarter q = c15>>2, 32 ch per quarter, 16B per lane
    int q = c15 >> 2;
    #pragma unroll
    for (int p = 0; p < 4; ++p) {
        int row_local = p * 4 + kc;
        int row = row0 + row_local;
        if (row < N) {
            uint4 vv = *(const uint4*)&bw[row_local * CH + c15 * 8];
            *(uint4*)&xwq[((size_t)q * N + row) * 32 + (c15 & 3) * 8] = vv;
        }
    }
}

// ---- Aggregation: out[i] = dinv[i] * (sum_j xwq[src_j] + xwq[i]) + b ----
// 4 lanes/node, 64 nodes/block; quarter q=(bid&7)>>1 -> one quarter per XCD
// pair -> 3.2MB sub-table is L2-resident. Masked unroll-8, nontemporal out.

__global__ __launch_bounds__(256) void agg_kernel(const ushort* __restrict__ xwq,
        const ushort* __restrict__ csr, const int* __restrict__ off,
        const float* __restrict__ dinv, const float* __restrict__ b,
        float* __restrict__ out, int N) {
    int t = threadIdx.x;
    int bid = blockIdx.x;
    int q = (bid & 7) >> 1;                   // quarter (XCD pair)
    int iw = (bid >> 3) * 2 + (bid & 1);      // node-block within quarter
    int node = iw * 64 + (t >> 2);
    if (node >= N) return;
    int lane4 = t & 3;                        // 8 ch per lane within quarter
    int s = off[node], e = off[node + 1];
    float acc[8] = {0.f,0.f,0.f,0.f,0.f,0.f,0.f,0.f};
    const ushort* base = xwq + (size_t)q * N * 32 + lane4 * 8;

    int last = e - 1;
    for (int j = s; j < e; j += 8) {
        int idx[8]; float m[8];
        #pragma unroll
        for (int k = 0; k < 8; ++k) {
            int jj = j + k;
            idx[k] = csr[min(jj, last)];
            m[k] = (jj <= last) ? 1.0f : 0.0f;
        }
        uint4 v[8];
        #pragma unroll
        for (int k = 0; k < 8; ++k)
            v[k] = *(const uint4*)(base + (size_t)idx[k] * 32);
        #pragma unroll
        for (int k = 0; k < 8; ++k) {
            acc[0] += m[k] * __uint_as_float(v[k].x << 16);
            acc[1] += m[k] * __uint_as_float(v[k].x & 0xffff0000u);
            acc[2] += m[k] * __uint_as_float(v[k].y << 16);
            acc[3] += m[k] * __uint_as_float(v[k].y & 0xffff0000u);
            acc[4] += m[k] * __uint_as_float(v[k].z << 16);
            acc[5] += m[k] * __uint_as_float(v[k].z & 0xffff0000u);
            acc[6] += m[k] * __uint_as_float(v[k].w << 16);
            acc[7] += m[k] * __uint_as_float(v[k].w & 0xffff0000u);
        }
    }
    {   // self loop term
        uint4 v = *(const uint4*)(base + (size_t)node * 32);
        acc[0] += __uint_as_float(v.x << 16);
        acc[1] += __uint_as_float(v.x & 0xffff0000u);
        acc[2] += __uint_as_float(v.y << 16);
        acc[3] += __uint_as_float(v.y & 0xffff0000u);
        acc[4] += __uint_as_float(v.z << 16);
        acc[5] += __uint_as_float(v.z & 0xffff0000u);
        acc[6] += __uint_as_float(v.w << 16);
        acc[7] += __uint_as_float(v.w & 0xffff0000u);
    }
    float di = dinv[node];
    int ch0 = q * 32 + lane4 * 8;
    float4 b0 = *(const float4*)&b[ch0];
    float4 b1 = *(const float4*)&b[ch0 + 4];
    f32x4 o0, o1;
    o0[0] = di * acc[0] + b0.x;  o0[1] = di * acc[1] + b0.y;
    o0[2] = di * acc[2] + b0.z;  o0[3] = di * acc[3] + b0.w;
    o1[0] = di * acc[4] + b1.x;  o1[1] = di * acc[5] + b1.y;
    o1[2] = di * acc[6] + b1.z;  o1[3] = di * acc[7] + b1.w;
    float* op = out + (size_t)node * CH + ch0;
    __builtin_nontemporal_store(o0, (f32x4*)op);
    __builtin_nontemporal_store(o1, (f32x4*)(op + 4));
}

// ---- launch -------------------------------------------------------------

extern "C" void kernel_launch(void* const* d_in, const int* in_sizes, int n_in,
                              void* d_out, int out_size, void* d_ws, size_t ws_size,
                              hipStream_t stream) {
    const float* x  = (const float*)d_in[0];
    const float* Wm = (const float*)d_in[1];
    const float* b  = (const float*)d_in[2];
    const int*   ei = (const int*)d_in[3];
    int N = in_sizes[0] / CH;
    int E = in_sizes[3] / 2;
    const int* src = ei;
    const int* dst = ei + E;
    float* out = (float*)d_out;

    char* w = (char*)d_ws;
    auto alloc = [&](size_t bytes) {
        char* p = w;
        w += (bytes + 255) & ~(size_t)255;
        return p;
    };
    int nc = (N + 255) >> 8;                     // 196 coarse buckets
    int nblk = (E + CHUNK - 1) / CHUNK;          // 196 binning blocks

    ushort*   xwq  = (ushort*)alloc((size_t)N * CH * 2);   // 4 x 3.2 MB quarters
    unsigned* ebuf = (unsigned*)xwq;                       // E*4 = 3.2 MB, dead before gemm
    int*      off  = (int*)alloc((size_t)(N + 1) * 4);
    ushort*   csr  = (ushort*)alloc((size_t)E * 2);
    float*    dinv = (float*)alloc((size_t)N * 4);
    ushort*   Wp   = (ushort*)alloc((size_t)16384 * 2);
    int*      h    = (int*)alloc((size_t)nc * nblk * 4);   // 154 KB
    int*      bbase= (int*)alloc((size_t)(nc + 1) * 4);
    int*      coltot=(int*)alloc((size_t)nc * 4);

    (void)hipMemsetAsync(coltot, 0, (size_t)nc * 4, stream);   // 784 B, capture-safe
    hist_kernel<<<nblk, 256, 0, stream>>>(dst, h, coltot, E, nc, nblk);
    colscan_cols<<<nc, 256, 0, stream>>>(h, coltot, bbase, nblk, nc);
    binscatter_kernel<<<nblk, 256, 0, stream>>>(src, dst, h, ebuf, E, nc, nblk);
    bucket_csr_packw<<<nc + 8, 256, 0, stream>>>(ebuf, bbase, off, csr, dinv, Wm, Wp, N, nc);
    gemm_mfma<<<(N + 63) / 64, 256, 0, stream>>>(x, Wp, dinv, xwq, N);
    int nbq = (N + 63) / 64;                     // node-blocks per quarter
    int agg_grid = ((nbq + 1) / 2) * 8;          // 4 quarters x 2 XCDs each
    agg_kernel<<<agg_grid, 256, 0, stream>>>(xwq, csr, off, dinv, b, out, N);
}